// Round 1
// baseline (1068.579 us; speedup 1.0000x reference)
//
#include <hip/hip_runtime.h>

// SSMBase: causal depthwise long conv + skip.
// y[b,l,d] = sum_{t=0..l} k[d,t] * x[b,l-t,d] + skip[d] * x[b,l,d]
// Shapes: x [B=4, L=4096, D=1024] f32, k [D, 4096] f32, skip [D] f32.
// Round 1: direct fp32 conv, register-blocked 16x16, LDS-staged sequences.
// Compute-bound: ~3.44e10 FMA on vector ALU (no fp32 MFMA on CDNA4).

#define BB 4
#define LL 4096
#define DD 1024
#define NT 256
#define RPT 16

// Generic batched transpose: in [B][R][C] -> out [B][C][R]
__global__ __launch_bounds__(256) void transpose_k(const float* __restrict__ in,
                                                   float* __restrict__ out,
                                                   int R, int C) {
    __shared__ float tile[32][33];
    int b = blockIdx.z;
    int c0 = blockIdx.x * 32;
    int r0 = blockIdx.y * 32;
    int tx = threadIdx.x;           // 0..31
    int ty = threadIdx.y;           // 0..7
#pragma unroll
    for (int i = 0; i < 4; i++) {
        int r = r0 + ty + i * 8;
        tile[ty + i * 8][tx] = in[((size_t)b * R + r) * C + c0 + tx];
    }
    __syncthreads();
#pragma unroll
    for (int i = 0; i < 4; i++) {
        int c = c0 + ty + i * 8;
        out[((size_t)b * C + c) * R + r0 + tx] = tile[tx][ty + i * 8];
    }
}

// xs LDS layout: logical index i in [0, L+16); value = (i<16 ? 0 : x[i-16]).
// physical addr p(i) = i + (i>>4)  (pad 1 float per 16 -> per-lane windows are
// stride-17 across lanes -> conflict-free).
#define XS_PHYS 4368  // max p(4111) = 4367

__global__ __launch_bounds__(256) void conv_direct(
        const float* __restrict__ xt,    // [B][D][L] (transposed) or nullptr
        const float* __restrict__ x_ld,  // original [B][L][D] (fallback load)
        const float* __restrict__ kw,    // [D][L]
        const float* __restrict__ skip,  // [D]
        float* __restrict__ yt,          // [B][D][L] (if !direct_out)
        float* __restrict__ out,         // [B][L][D] (if direct_out)
        int use_xt, int direct_out) {
    __shared__ float ks[LL];
    __shared__ float xs[XS_PHYS];
    int tid = threadIdx.x;
    int bid = blockIdx.x;
    int d = bid & (DD - 1);
    int b = bid >> 10;

    const float* krow = kw + (size_t)d * LL;
#pragma unroll
    for (int i = 0; i < LL; i += NT) ks[i + tid] = krow[i + tid];

    if (use_xt) {
        const float* xrow = xt + ((size_t)b * DD + d) * LL;
        for (int i = tid; i < LL + 16; i += NT) {
            float v = (i < 16) ? 0.0f : xrow[i - 16];
            xs[i + (i >> 4)] = v;
        }
    } else {
        for (int i = tid; i < LL + 16; i += NT) {
            float v = (i < 16) ? 0.0f : x_ld[((size_t)b * LL + (i - 16)) * DD + d];
            xs[i + (i >> 4)] = v;
        }
    }
    __syncthreads();

    float acc[RPT];
#pragma unroll
    for (int r = 0; r < RPT; r++) acc[r] = 0.0f;

#pragma unroll 1
    for (int c = 0; c <= tid; ++c) {
        int t0 = c << 4;
        float kk[16];
#pragma unroll
        for (int j = 0; j < 16; j++) kk[j] = ks[t0 + j];  // uniform -> broadcast
        // x window: logical stored idx base = 16*(tid-c)+1, 31 values.
        // physical = 17*(tid-c) + 1 + u + (u>=15)
        int pb = (tid - c) * 17 + 1;
        float xx[31];
#pragma unroll
        for (int u = 0; u < 31; u++) xx[u] = xs[pb + u + (u >= 15 ? 1 : 0)];
#pragma unroll
        for (int j = 0; j < 16; j++) {
#pragma unroll
            for (int r = 0; r < RPT; r++) {
                acc[r] = fmaf(kk[j], xx[15 + r - j], acc[r]);
            }
        }
    }

    // skip epilogue: x[l0+r] lives at physical 17*(tid+1)+r
    float sk = skip[d];
    int pe = 17 * (tid + 1);
#pragma unroll
    for (int r = 0; r < RPT; r++) acc[r] = fmaf(sk, xs[pe + r], acc[r]);

    int l0 = tid << 4;
    if (direct_out) {
#pragma unroll
        for (int r = 0; r < RPT; r++)
            out[((size_t)b * LL + l0 + r) * DD + d] = acc[r];
    } else {
        float4* dst = (float4*)(yt + ((size_t)b * DD + d) * LL + l0);
#pragma unroll
        for (int r4 = 0; r4 < 4; r4++) {
            float4 v;
            v.x = acc[r4 * 4 + 0];
            v.y = acc[r4 * 4 + 1];
            v.z = acc[r4 * 4 + 2];
            v.w = acc[r4 * 4 + 3];
            dst[r4] = v;
        }
    }
}

extern "C" void kernel_launch(void* const* d_in, const int* in_sizes, int n_in,
                              void* d_out, int out_size, void* d_ws, size_t ws_size,
                              hipStream_t stream) {
    const float* x    = (const float*)d_in[0];  // [B,L,D]
    const float* kw   = (const float*)d_in[1];  // [D,KD=L]
    const float* skip = (const float*)d_in[2];  // [D]
    float* out = (float*)d_out;                 // [B,L,D]

    size_t buf_elems = (size_t)BB * DD * LL;
    size_t buf_bytes = buf_elems * sizeof(float);
    int have_xt = ws_size >= buf_bytes;
    int have_yt = ws_size >= 2 * buf_bytes;
    float* xt = (float*)d_ws;
    float* yt = have_yt ? (float*)((char*)d_ws + buf_bytes) : nullptr;

    dim3 tb(32, 8);
    if (have_xt) {
        // x [B, R=L, C=D] -> xt [B, D, L]
        transpose_k<<<dim3(DD / 32, LL / 32, BB), tb, 0, stream>>>(x, xt, LL, DD);
    }
    conv_direct<<<dim3(BB * DD), NT, 0, stream>>>(
        have_xt ? xt : nullptr, x, kw, skip,
        yt, out, have_xt ? 1 : 0, have_yt ? 0 : 1);
    if (have_yt) {
        // yt [B, R=D, C=L] -> out [B, L, D]
        transpose_k<<<dim3(LL / 32, DD / 32, BB), tb, 0, stream>>>(yt, out, DD, LL);
    }
}

// Round 2
// 263.283 us; speedup vs baseline: 4.0587x; 4.0587x over previous
//
#include <hip/hip_runtime.h>

// SSMBase: causal depthwise long conv + skip, via bf16 MFMA block-Toeplitz.
// y[b,l,d] = sum_t k[d,t] x[b,l-t,d] + skip[d] x[b,l,d]
// x [4,4096,1024] f32, k [1024,4096] f32, skip [1024] f32.
// Pipeline: transpose x -> xt bf16 [B][D][L]; conv_mfma -> yt f32 [B][D][L];
// transpose back + skip-add. MFMA 32x32x16_bf16, fp32 accumulate.

#define BB 4
#define LL 4096
#define DD 1024

typedef __attribute__((ext_vector_type(8))) short short8;
typedef __attribute__((ext_vector_type(16))) float f32x16;

__device__ __forceinline__ unsigned short f2bf(float f) {
    unsigned int u = __builtin_bit_cast(unsigned int, f);
    u += 0x7fffu + ((u >> 16) & 1u);
    return (unsigned short)(u >> 16);
}

// x [B][L][D] f32 -> xt [B][D][L] bf16
__global__ __launch_bounds__(256) void transpose_x_bf16(const float* __restrict__ in,
                                                        unsigned short* __restrict__ out) {
    __shared__ float tile[32][33];
    int b = blockIdx.z;
    int c0 = blockIdx.x * 32;   // D
    int r0 = blockIdx.y * 32;   // L
    int tx = threadIdx.x, ty = threadIdx.y;
#pragma unroll
    for (int i = 0; i < 4; i++) {
        int r = r0 + ty + i * 8;
        tile[ty + i * 8][tx] = in[((size_t)b * LL + r) * DD + c0 + tx];
    }
    __syncthreads();
#pragma unroll
    for (int i = 0; i < 4; i++) {
        int c = c0 + ty + i * 8;
        out[((size_t)b * DD + c) * LL + r0 + tx] = f2bf(tile[tx][ty + i * 8]);
    }
}

// yt [B][D][L] f32 -> out [B][L][D] f32, fused skip: out = yt^T + skip[d]*x
__global__ __launch_bounds__(256) void transpose_y_skip(const float* __restrict__ yt,
                                                        const float* __restrict__ x,
                                                        const float* __restrict__ skip,
                                                        float* __restrict__ out) {
    __shared__ float tile[32][33];
    int b = blockIdx.z;
    int c0 = blockIdx.x * 32;   // L
    int r0 = blockIdx.y * 32;   // D
    int tx = threadIdx.x, ty = threadIdx.y;
#pragma unroll
    for (int i = 0; i < 4; i++) {
        int r = r0 + ty + i * 8;
        tile[ty + i * 8][tx] = yt[((size_t)b * DD + r) * LL + c0 + tx];
    }
    float sv = skip[r0 + tx];
    __syncthreads();
#pragma unroll
    for (int i = 0; i < 4; i++) {
        int c = c0 + ty + i * 8;
        size_t oi = ((size_t)b * LL + c) * DD + r0 + tx;
        out[oi] = tile[tx][ty + i * 8] + sv * x[oi];
    }
}

// MFMA conv. One block = 2 channels d (sequential phases), 8 waves.
// Per d: columns = (b,i) pairs, col c_global = 4*(PAD+i) + b, PAD=8 zero blocks.
// Tile t (t=0..15): cols i in [8t,8t+8), all 4 b. Wave w owns tiles {w, 15-w}.
// A (Toeplitz k): lane l holds A[r=l&31][s=16q+8h+f] = k[32m+r-s] = krev[4095-32m-r+s],
//   fetched from pair-duplicated krev2x[j] = krev[j] | krev[j+1]<<16 (words a0+2v).
// B (x): lane l holds B[s][col=l&31] = x[b][32*(i-m)+s]; 16B/lane from swizzled xbuf.
// xbuf layout: col c, slot s>>3 rotated by c: byte = 64c + 16*((s>>3 + c)&3) + 2*(s&7).
__global__ __launch_bounds__(512, 1) void conv_mfma(
        const unsigned short* __restrict__ xt,  // [B][D][L] bf16
        const float* __restrict__ kw,           // [D][LL] f32
        float* __restrict__ yt) {               // [B][D][L] f32
    __shared__ unsigned int krev2x[4128];
    __shared__ unsigned char xbuf[34816];       // (8+128) blocks * 4 b * 64B
    const int tid = threadIdx.x;
    const int lane = tid & 63;
    const int w = tid >> 6;
    const int lam = lane & 31;
    const int h = lane >> 5;

    for (int phase = 0; phase < 2; ++phase) {
        const int d = (blockIdx.x << 1) + phase;

        // ---- stage krev2x: word j = bf16(k[4095-j]) | bf16(k[4094-j])<<16 ----
        {
            const float* krow = kw + (size_t)d * LL;
            int j0 = tid << 3;
#pragma unroll
            for (int f = 0; f < 8; ++f) {
                int j = j0 + f;
                int i2 = 4094 - j;
                unsigned int lo = f2bf(krow[4095 - j]);
                unsigned int hi = (i2 >= 0) ? (unsigned int)f2bf(krow[i2]) : 0u;
                krev2x[j] = lo | (hi << 16);
            }
            if (tid < 32) krev2x[4096 + tid] = 0u;
        }
        // ---- stage xbuf (16B per slot, slot-rotated) ----
        for (int sid = tid; sid < 2176; sid += 512) {
            int c = sid >> 2, sraw = sid & 3;
            int J = c >> 2, b2 = c & 3;
            int ix = J - 8;
            uint4 v = {0u, 0u, 0u, 0u};
            if (ix >= 0)
                v = *(const uint4*)(xt + (((size_t)b2 * DD + d) * LL) + (ix << 5) + (sraw << 3));
            *(uint4*)(xbuf + (c << 6) + ((((sraw + c) & 3)) << 4)) = v;
        }
        __syncthreads();

        // ---- compute ----
        const int ta = w, tb = 15 - w;
        const int mmax_a = 8 * ta + 7;
        const int mmax_b = 8 * tb + 7;
        f32x16 acca, accb;
#pragma unroll
        for (int i = 0; i < 16; i++) { acca[i] = 0.f; accb[i] = 0.f; }

        for (int m = 0; m <= mmax_b; ++m) {
            const int c_a = ((8 + 8 * ta - m) << 2) + lam;
            const int c_b = ((8 + 8 * tb - m) << 2) + lam;
            const int a0m = 4095 - (m << 5) - lam + (h << 3);
#pragma unroll
            for (int q = 0; q < 2; ++q) {
                int a0 = a0m + (q << 4);
                unsigned int w0 = krev2x[a0];
                unsigned int w1 = krev2x[a0 + 2];
                unsigned int w2 = krev2x[a0 + 4];
                unsigned int w3 = krev2x[a0 + 6];
                struct U4 { unsigned int a, b, c, d; };
                U4 au{w0, w1, w2, w3};
                short8 af = __builtin_bit_cast(short8, au);
                int sq = (q << 1) + h;
                short8 bfb = *(const short8*)(xbuf + (c_b << 6) + ((((sq + c_b) & 3)) << 4));
                accb = __builtin_amdgcn_mfma_f32_32x32x16_bf16(af, bfb, accb, 0, 0, 0);
                if (m <= mmax_a) {
                    short8 bfa = *(const short8*)(xbuf + (c_a << 6) + ((((sq + c_a) & 3)) << 4));
                    acca = __builtin_amdgcn_mfma_f32_32x32x16_bf16(af, bfa, acca, 0, 0, 0);
                }
            }
        }
        __syncthreads();

        // ---- writeback via LDS transpose (wave-private region) ----
        // D layout: col=lane&31, row=(reg&3)+8*(reg>>2)+4*h  -> slot_raw=row/4=2g+h
        unsigned char* wr = xbuf + w * 4352;
#pragma unroll
        for (int tt = 0; tt < 2; ++tt) {
            int t = tt ? tb : ta;
            const f32x16& ac = tt ? accb : acca;
#pragma unroll
            for (int g = 0; g < 4; ++g) {
                float4 v = make_float4(ac[4 * g + 0], ac[4 * g + 1],
                                       ac[4 * g + 2], ac[4 * g + 3]);
                int sraw = (g << 1) + h;
                *(float4*)(wr + (lam << 7) + ((((sraw + lam) & 7)) << 4)) = v;
            }
#pragma unroll
            for (int j = 0; j < 4; ++j) {
                int colr = (lane >> 3) + (j << 3);
                int sr = lane & 7;
                float4 v = *(const float4*)(wr + (colr << 7) + ((((sr + colr) & 7)) << 4));
                int ii = (t << 3) + (colr >> 2);
                int b2 = colr & 3;
                *(float4*)(yt + (((size_t)b2 * DD + d) * LL) + (ii << 5) + (sr << 2)) = v;
            }
        }
        __syncthreads();
    }
}

// ---- round-1 fallback (ws too small): direct fp32 conv, strided I/O ----
#define NT 256
#define RPT 16
#define XS_PHYS 4368

__global__ __launch_bounds__(256) void conv_direct(
        const float* __restrict__ x_ld,  // [B][L][D]
        const float* __restrict__ kw,
        const float* __restrict__ skip,
        float* __restrict__ out) {
    __shared__ float ks[LL];
    __shared__ float xs[XS_PHYS];
    int tid = threadIdx.x;
    int bid = blockIdx.x;
    int d = bid & (DD - 1);
    int b = bid >> 10;
    const float* krow = kw + (size_t)d * LL;
#pragma unroll
    for (int i = 0; i < LL; i += NT) ks[i + tid] = krow[i + tid];
    for (int i = tid; i < LL + 16; i += NT) {
        float v = (i < 16) ? 0.0f : x_ld[((size_t)b * LL + (i - 16)) * DD + d];
        xs[i + (i >> 4)] = v;
    }
    __syncthreads();
    float acc[RPT];
#pragma unroll
    for (int r = 0; r < RPT; r++) acc[r] = 0.0f;
#pragma unroll 1
    for (int c = 0; c <= tid; ++c) {
        int t0 = c << 4;
        float kk[16];
#pragma unroll
        for (int j = 0; j < 16; j++) kk[j] = ks[t0 + j];
        int pb = (tid - c) * 17 + 1;
        float xx[31];
#pragma unroll
        for (int u = 0; u < 31; u++) xx[u] = xs[pb + u + (u >= 15 ? 1 : 0)];
#pragma unroll
        for (int j = 0; j < 16; j++) {
#pragma unroll
            for (int r = 0; r < RPT; r++) acc[r] = fmaf(kk[j], xx[15 + r - j], acc[r]);
        }
    }
    float sk = skip[d];
    int pe = 17 * (tid + 1);
#pragma unroll
    for (int r = 0; r < RPT; r++) acc[r] = fmaf(sk, xs[pe + r], acc[r]);
    int l0 = tid << 4;
#pragma unroll
    for (int r = 0; r < RPT; r++)
        out[((size_t)b * LL + l0 + r) * DD + d] = acc[r];
}

extern "C" void kernel_launch(void* const* d_in, const int* in_sizes, int n_in,
                              void* d_out, int out_size, void* d_ws, size_t ws_size,
                              hipStream_t stream) {
    const float* x    = (const float*)d_in[0];
    const float* kw   = (const float*)d_in[1];
    const float* skip = (const float*)d_in[2];
    float* out = (float*)d_out;

    size_t xt_bytes = (size_t)BB * DD * LL * 2;   // 32 MB bf16
    size_t yt_bytes = (size_t)BB * DD * LL * 4;   // 64 MB f32

    if (ws_size >= xt_bytes + yt_bytes) {
        unsigned short* xt = (unsigned short*)d_ws;
        float* yt = (float*)((char*)d_ws + xt_bytes);
        transpose_x_bf16<<<dim3(DD / 32, LL / 32, BB), dim3(32, 8), 0, stream>>>(x, xt);
        conv_mfma<<<dim3(DD / 2), dim3(512), 0, stream>>>(xt, kw, yt);
        transpose_y_skip<<<dim3(LL / 32, DD / 32, BB), dim3(32, 8), 0, stream>>>(yt, x, skip, out);
    } else {
        conv_direct<<<dim3(BB * DD), NT, 0, stream>>>(x, kw, skip, out);
    }
}

// Round 3
// 225.458 us; speedup vs baseline: 4.7396x; 1.1678x over previous
//
#include <hip/hip_runtime.h>

// SSMBase: causal depthwise long conv + skip, bf16 MFMA block-Toeplitz.
// y[b,l,d] = sum_t k[d,t] x[b,l-t,d] + skip[d] x[b,l,d]
// x [4,4096,1024] f32, k [1024,4096] f32, skip [1024] f32.
// R3: conflict-free 80B xbuf stride, circular-B register buffer (adjacent
// tile pairs, 1 B-load per 2 MFMAs), direct reg->global writeback,
// float4-vectorized transposes.

#define BB 4
#define LL 4096
#define DD 1024

typedef __attribute__((ext_vector_type(8))) short short8;
typedef __attribute__((ext_vector_type(16))) float f32x16;

__device__ __forceinline__ unsigned short f2bf(float f) {
    unsigned int u = __builtin_bit_cast(unsigned int, f);
    u += 0x7fffu + ((u >> 16) & 1u);
    return (unsigned short)(u >> 16);
}

// ---------------- transpose x: [B][L][D] f32 -> [B][D][L] bf16 ----------------
__global__ __launch_bounds__(256) void transpose_x_bf16(const float* __restrict__ in,
                                                        unsigned short* __restrict__ out) {
    __shared__ float tile[64][65];   // [d][l], +1 pad: scalar r/w conflict-free
    int b = blockIdx.z;
    int d0 = blockIdx.x * 64;
    int l0 = blockIdx.y * 64;
    int tid = threadIdx.x;
    int u = tid & 15, v = tid >> 4;
#pragma unroll
    for (int rr = 0; rr < 4; rr++) {
        int l = v + 16 * rr;
        float4 t4 = *(const float4*)&in[((size_t)b * LL + l0 + l) * DD + d0 + 4 * u];
        tile[4 * u + 0][l] = t4.x;
        tile[4 * u + 1][l] = t4.y;
        tile[4 * u + 2][l] = t4.z;
        tile[4 * u + 3][l] = t4.w;
    }
    __syncthreads();
    int dd = tid & 63;
    int jg = tid >> 6;
#pragma unroll
    for (int it = 0; it < 2; it++) {
        int jj = jg + 4 * it;
        unsigned short pk[8];
#pragma unroll
        for (int e = 0; e < 8; e++) pk[e] = f2bf(tile[dd][8 * jj + e]);
        *(uint4*)&out[((size_t)b * DD + d0 + dd) * LL + l0 + 8 * jj] =
            *(const uint4*)pk;
    }
}

// -------- transpose y + skip: out[b][l][d] = yt[b][d][l] + skip[d]*x[b][l][d] --------
__global__ __launch_bounds__(256) void transpose_y_skip(const float* __restrict__ yt,
                                                        const float* __restrict__ x,
                                                        const float* __restrict__ skip,
                                                        float* __restrict__ out) {
    __shared__ float tile[64][65];   // [l][d]
    int b = blockIdx.z;
    int d0 = blockIdx.x * 64;
    int l0 = blockIdx.y * 64;
    int tid = threadIdx.x;
    int u = tid & 15, v = tid >> 4;
#pragma unroll
    for (int rr = 0; rr < 4; rr++) {
        int dd = v + 16 * rr;
        float4 t4 = *(const float4*)&yt[((size_t)b * DD + d0 + dd) * LL + l0 + 4 * u];
        tile[4 * u + 0][dd] = t4.x;
        tile[4 * u + 1][dd] = t4.y;
        tile[4 * u + 2][dd] = t4.z;
        tile[4 * u + 3][dd] = t4.w;
    }
    __syncthreads();
    int ug = tid & 15, lr = tid >> 4;
    float4 sk4 = *(const float4*)&skip[d0 + 4 * ug];
#pragma unroll
    for (int rr = 0; rr < 4; rr++) {
        int l = lr + 16 * rr;
        size_t oi = ((size_t)b * LL + l0 + l) * DD + d0 + 4 * ug;
        float4 x4 = *(const float4*)&x[oi];
        float4 o4;
        o4.x = tile[l][4 * ug + 0] + sk4.x * x4.x;
        o4.y = tile[l][4 * ug + 1] + sk4.y * x4.y;
        o4.z = tile[l][4 * ug + 2] + sk4.z * x4.z;
        o4.w = tile[l][4 * ug + 3] + sk4.w * x4.w;
        *(float4*)&out[oi] = o4;
    }
}

// ---------------- conv: one block = one channel d, 8 waves ----------------
// Columns of a 32-col tile t: i = 8t + (lam>>2), b = lam&3  (c = 4J + lam).
// xbuf: col c stride 80B (20 banks -> conflict-free b128), slot s = 2q+h at +16*s.
// A (Toeplitz k): lane reads krev2x[a0+{0,2,4,6}], a0 = 4095-32m-lam+8h+16q.
// Wave w owns tile pair p = (d&1)? 7-w : w  -> tiles {2p, 2p+1}; circular
// 8-slot B buffer: t1's operand at m == t0's fresh load at m-8.
__global__ __launch_bounds__(512, 4) void conv_mfma(
        const unsigned short* __restrict__ xt,  // [B][D][L] bf16
        const float* __restrict__ kw,           // [D][LL] f32
        float* __restrict__ yt) {               // [B][D][L] f32
    __shared__ unsigned int krev2x[4128];
    __shared__ unsigned char xbuf[43520];       // 544 cols * 80B
    const int tid = threadIdx.x;
    const int lane = tid & 63;
    const int w = tid >> 6;
    const int lam = lane & 31;
    const int h = lane >> 5;
    const int d = blockIdx.x;

    // stage krev2x: word j = bf16(k[4095-j]) | bf16(k[4094-j])<<16
    {
        const float* krow = kw + (size_t)d * LL;
        int j0 = tid << 3;
#pragma unroll
        for (int f = 0; f < 8; ++f) {
            int j = j0 + f;
            unsigned int lo = f2bf(krow[4095 - j]);
            unsigned int hi = (j < 4095) ? (unsigned int)f2bf(krow[4094 - j]) : 0u;
            krev2x[j] = lo | (hi << 16);
        }
        if (tid < 32) krev2x[4096 + tid] = 0u;
    }
    // stage xbuf: col c = 4J+b, J=0..135 (8 zero-pad + 128 x-blocks)
    for (int sid = tid; sid < 2176; sid += 512) {
        int c = sid >> 2, sr = sid & 3;
        int J = c >> 2, b2 = c & 3;
        int ix = J - 8;
        uint4 v = {0u, 0u, 0u, 0u};
        if (ix >= 0)
            v = *(const uint4*)(xt + (((size_t)b2 * DD + d) * LL) + (ix << 5) + (sr << 3));
        *(uint4*)(xbuf + c * 80 + sr * 16) = v;
    }
    __syncthreads();

    const int p = (d & 1) ? (7 - w) : w;
    const int t0 = 2 * p, t1 = 2 * p + 1;
    const int nb = 2 * p + 2;                   // unroll-8 blocks (iters = 16p+16)

    f32x16 acc0, acc1;
#pragma unroll
    for (int i = 0; i < 16; i++) { acc0[i] = 0.f; acc1[i] = 0.f; }

#pragma unroll
    for (int q = 0; q < 2; ++q) {
        const int slot16 = (2 * q + h) * 16;
        const int abase = 4095 - lam + 8 * h + 16 * q;
        const unsigned char* xb = xbuf + lam * 80 + slot16;
        short8 buf[8];

        // ---- first 8-block (m=0..7): fresh loads for BOTH tiles ----
#pragma unroll
        for (int j = 0; j < 8; ++j) {
            int m = j;
            int a = abase - (m << 5);
            unsigned int w0 = krev2x[a], w1 = krev2x[a + 2];
            unsigned int w2 = krev2x[a + 4], w3 = krev2x[a + 6];
            struct U4 { unsigned int a, b, c, d; };
            U4 au{w0, w1, w2, w3};
            short8 af = __builtin_bit_cast(short8, au);
            short8 f0 = *(const short8*)(xb + (8 + 8 * t0 - m) * 320);
            short8 f1 = *(const short8*)(xb + (8 + 8 * t1 - m) * 320);
            acc0 = __builtin_amdgcn_mfma_f32_32x32x16_bf16(af, f0, acc0, 0, 0, 0);
            acc1 = __builtin_amdgcn_mfma_f32_32x32x16_bf16(af, f1, acc1, 0, 0, 0);
            buf[j] = f0;
        }
        // ---- middle blocks: 1 fresh load serves both tiles ----
        for (int blk = 1; blk <= nb - 2; ++blk) {
#pragma unroll
            for (int j = 0; j < 8; ++j) {
                int m = (blk << 3) + j;
                int a = abase - (m << 5);
                unsigned int w0 = krev2x[a], w1 = krev2x[a + 2];
                unsigned int w2 = krev2x[a + 4], w3 = krev2x[a + 6];
                struct U4 { unsigned int a, b, c, d; };
                U4 au{w0, w1, w2, w3};
                short8 af = __builtin_bit_cast(short8, au);
                short8 f0 = *(const short8*)(xb + (8 + 8 * t0 - m) * 320);
                acc1 = __builtin_amdgcn_mfma_f32_32x32x16_bf16(af, buf[j], acc1, 0, 0, 0);
                acc0 = __builtin_amdgcn_mfma_f32_32x32x16_bf16(af, f0, acc0, 0, 0, 0);
                buf[j] = f0;
            }
        }
        // ---- last 8-block: consume-only for t1 ----
#pragma unroll
        for (int j = 0; j < 8; ++j) {
            int m = ((nb - 1) << 3) + j;
            int a = abase - (m << 5);
            unsigned int w0 = krev2x[a], w1 = krev2x[a + 2];
            unsigned int w2 = krev2x[a + 4], w3 = krev2x[a + 6];
            struct U4 { unsigned int a, b, c, d; };
            U4 au{w0, w1, w2, w3};
            short8 af = __builtin_bit_cast(short8, au);
            acc1 = __builtin_amdgcn_mfma_f32_32x32x16_bf16(af, buf[j], acc1, 0, 0, 0);
        }
    }

    // ---- direct writeback: D layout col=lane&31, row=(reg&3)+8*(reg>>2)+4h ----
    const int b2 = lam & 3;
    const int j2 = lam >> 2;
#pragma unroll
    for (int tt = 0; tt < 2; ++tt) {
        int t = tt ? t1 : t0;
        const f32x16& ac = tt ? acc1 : acc0;
        int i = 8 * t + j2;
        float* base = yt + (((size_t)b2 * DD + d) * LL) + (i << 5) + 4 * h;
#pragma unroll
        for (int g = 0; g < 4; ++g) {
            float4 v = make_float4(ac[4 * g + 0], ac[4 * g + 1],
                                   ac[4 * g + 2], ac[4 * g + 3]);
            *(float4*)(base + 8 * g) = v;
        }
    }
}

// ---------------- fallback (ws too small): direct fp32 conv ----------------
#define NT 256
#define RPT 16
#define XS_PHYS 4368

__global__ __launch_bounds__(256) void conv_direct(
        const float* __restrict__ x_ld,
        const float* __restrict__ kw,
        const float* __restrict__ skip,
        float* __restrict__ out) {
    __shared__ float ks[LL];
    __shared__ float xs[XS_PHYS];
    int tid = threadIdx.x;
    int bid = blockIdx.x;
    int d = bid & (DD - 1);
    int b = bid >> 10;
    const float* krow = kw + (size_t)d * LL;
#pragma unroll
    for (int i = 0; i < LL; i += NT) ks[i + tid] = krow[i + tid];
    for (int i = tid; i < LL + 16; i += NT) {
        float v = (i < 16) ? 0.0f : x_ld[((size_t)b * LL + (i - 16)) * DD + d];
        xs[i + (i >> 4)] = v;
    }
    __syncthreads();
    float acc[RPT];
#pragma unroll
    for (int r = 0; r < RPT; r++) acc[r] = 0.0f;
#pragma unroll 1
    for (int c = 0; c <= tid; ++c) {
        int tt0 = c << 4;
        float kk[16];
#pragma unroll
        for (int j = 0; j < 16; j++) kk[j] = ks[tt0 + j];
        int pb = (tid - c) * 17 + 1;
        float xx[31];
#pragma unroll
        for (int u = 0; u < 31; u++) xx[u] = xs[pb + u + (u >= 15 ? 1 : 0)];
#pragma unroll
        for (int j = 0; j < 16; j++) {
#pragma unroll
            for (int r = 0; r < RPT; r++) acc[r] = fmaf(kk[j], xx[15 + r - j], acc[r]);
        }
    }
    float sk = skip[d];
    int pe = 17 * (tid + 1);
#pragma unroll
    for (int r = 0; r < RPT; r++) acc[r] = fmaf(sk, xs[pe + r], acc[r]);
    int l0 = tid << 4;
#pragma unroll
    for (int r = 0; r < RPT; r++)
        out[((size_t)b * LL + l0 + r) * DD + d] = acc[r];
}

extern "C" void kernel_launch(void* const* d_in, const int* in_sizes, int n_in,
                              void* d_out, int out_size, void* d_ws, size_t ws_size,
                              hipStream_t stream) {
    const float* x    = (const float*)d_in[0];
    const float* kw   = (const float*)d_in[1];
    const float* skip = (const float*)d_in[2];
    float* out = (float*)d_out;

    size_t xt_bytes = (size_t)BB * DD * LL * 2;   // 32 MB bf16
    size_t yt_bytes = (size_t)BB * DD * LL * 4;   // 64 MB f32

    if (ws_size >= xt_bytes + yt_bytes) {
        unsigned short* xt = (unsigned short*)d_ws;
        float* yt = (float*)((char*)d_ws + xt_bytes);
        transpose_x_bf16<<<dim3(DD / 64, LL / 64, BB), dim3(256), 0, stream>>>(x, xt);
        conv_mfma<<<dim3(DD), dim3(512), 0, stream>>>(xt, kw, yt);
        transpose_y_skip<<<dim3(DD / 64, LL / 64, BB), dim3(256), 0, stream>>>(yt, x, skip, out);
    } else {
        conv_direct<<<dim3(BB * DD), NT, 0, stream>>>(x, kw, skip, out);
    }
}